// Round 1
// baseline (133.456 us; speedup 1.0000x reference)
//
#include <hip/hip_runtime.h>

// Correlation layer: in1,in2 [8,256,128,128] f32 -> out [8,81,128,128] f32
// out[b, dy*9+dx, y, x] = mean_c in1[b,c,y,x] * in2pad[b,c,y+dy,x+dx], pad=4
//
// MFMA formulation: per (row y, 16-pixel x-tile, dy):
//   D[i][j] = sum_c in1[c, x0+i] * in2p[c, y+dy, x0+j],  j in [0,24)
//   out(i, dx) = D[i][i+dx] / 256
// 2x mfma_f32_16x16x32_bf16 per (dy, 32-ch chunk), 9 dy accumulated in regs.

#define B_  8
#define C_  256
#define H_  128
#define W_  128
#define ND  9      // displacements per axis
#define TY  8      // rows per block (one per wave)
#define TW  16     // pixels per wave (x)
#define KC  32     // channels per chunk
#define KB  4      // KC/8 k-blocks
#define RR  16     // staged rows = TY+8
#define JJ  32     // staged cols (24 used, rest zero)

typedef short v8s __attribute__((ext_vector_type(8)));
typedef float v4f __attribute__((ext_vector_type(4)));

__device__ __forceinline__ unsigned short f2bf(float f) {
    union { float f; unsigned u; } v; v.f = f;
    return (unsigned short)((v.u + 0x7FFFu + ((v.u >> 16) & 1u)) >> 16);
}

__global__ __launch_bounds__(512, 4)
void corr_mfma_kernel(const float* __restrict__ in1,
                      const float* __restrict__ in2,
                      float* __restrict__ out) {
    // B operand staged bf16, pre-swizzled to fragment order: [kb][r][j][e]
    __shared__ __align__(16) short Blds[KB * RR * JJ * 8];   // 32 KB

    const int tid  = threadIdx.x;
    const int lane = tid & 63;
    const int w    = tid >> 6;        // wave id 0..7 -> row offset within tile
    const int x0   = blockIdx.x * TW;
    const int y0   = blockIdx.y * TY;
    const int b    = blockIdx.z;

    const int i_px = lane & 15;       // A row (pixel) / B col within N-tile
    const int kb   = lane >> 4;       // k-block 0..3

    v4f acc[ND][2];
    #pragma unroll
    for (int d = 0; d < ND; ++d) {
        acc[d][0] = (v4f)0.0f;
        acc[d][1] = (v4f)0.0f;
    }

    const long cs = (long)H_ * W_;    // channel stride (elements)
    const float* in1base =
        in1 + (((long)b * C_) * H_ + (y0 + w)) * W_ + x0 + i_px;

    for (int c0 = 0; c0 < C_; c0 += KC) {
        __syncthreads();  // previous chunk's MFMAs done before overwrite

        // ---- stage in2 chunk -> LDS (bf16, B-fragment swizzled) ----
        #pragma unroll
        for (int s4 = 0; s4 < 4; ++s4) {
            const int s   = tid + s4 * 512;   // 0..2047 = KB*RR*JJ
            const int j   = s & 31;
            const int r   = (s >> 5) & 15;
            const int skb = s >> 9;           // 0..3
            const int gy  = y0 - 4 + r;
            const int gx  = x0 - 4 + j;
            v8s pack;
            if (j < 24 && (unsigned)gy < (unsigned)H_ && (unsigned)gx < (unsigned)W_) {
                const float* p =
                    in2 + (((long)b * C_ + c0 + skb * 8) * H_ + gy) * W_ + gx;
                #pragma unroll
                for (int e = 0; e < 8; ++e)
                    pack[e] = (short)f2bf(p[e * cs]);
            } else {
                pack = (v8s)0;
            }
            *(v8s*)&Blds[((skb * RR + r) * JJ + j) * 8] = pack;
        }

        // ---- A fragment: in1, direct from global (read exactly once) ----
        v8s afrag;
        {
            const float* p = in1base + (long)(c0 + kb * 8) * cs;
            #pragma unroll
            for (int e = 0; e < 8; ++e)
                afrag[e] = (short)f2bf(p[e * cs]);
        }

        __syncthreads();  // staging visible to all waves

        // ---- 9 dy x 2 N-tiles MFMAs ----
        #pragma unroll
        for (int dy = 0; dy < ND; ++dy) {
            const int r = w + dy;             // staged row index, 0..15
            #pragma unroll
            for (int t = 0; t < 2; ++t) {
                const v8s bfrag =
                    *(const v8s*)&Blds[((kb * RR + r) * JJ + (t * 16 + i_px)) * 8];
                acc[dy][t] = __builtin_amdgcn_mfma_f32_16x16x32_bf16(
                    afrag, bfrag, acc[dy][t], 0, 0, 0);
            }
        }
    }

    // ---- epilogue: extract diagonals D[i][i+dx] via LDS bounce ----
    __syncthreads();                  // all waves done reading Blds as B
    float* ep  = (float*)Blds;        // reuse: [wave][16 rows i][24 cols j]
    float* epw = ep + w * (16 * 24);
    const int g = lane >> 4;          // 0..3

    for (int dy = 0; dy < ND; ++dy) {
        // scatter: lane holds D[row=(lane>>4)*4+q][col=t*16+(lane&15)]
        #pragma unroll
        for (int t = 0; t < 2; ++t) {
            const int j = t * 16 + i_px;
            if (j < 24) {
                #pragma unroll
                for (int q = 0; q < 4; ++q) {
                    const int i = g * 4 + q;
                    epw[i * 24 + j] = acc[dy][t][q];
                }
            }
        }
        __syncthreads();
        // gather diagonals + coalesced store
        #pragma unroll
        for (int rep = 0; rep < 3; ++rep) {
            const int dx = g + rep * 4;
            if (dx < 9) {
                const float v = epw[i_px * 24 + (i_px + dx)] * (1.0f / 256.0f);
                out[((((long)b * 81) + dy * 9 + dx) * H_ + (y0 + w)) * W_ + x0 + i_px] = v;
            }
        }
        __syncthreads();
    }
}

extern "C" void kernel_launch(void* const* d_in, const int* in_sizes, int n_in,
                              void* d_out, int out_size, void* d_ws, size_t ws_size,
                              hipStream_t stream) {
    const float* in1 = (const float*)d_in[0];
    const float* in2 = (const float*)d_in[1];
    float* outp      = (float*)d_out;
    dim3 grid(W_ / TW, H_ / TY, B_);   // (8, 16, 8) = 1024 blocks
    corr_mfma_kernel<<<grid, 512, 0, stream>>>(in1, in2, outp);
}